// Round 8
// baseline (286.981 us; speedup 1.0000x reference)
//
#include <hip/hip_runtime.h>

#define NN 50000
#define NE 1600000
#define DIM 128
#define NG  512
#define NCH 391        // ceil(NE/4096) edge chunks
#define CHSZ 4096
#define NBINS 196      // bin = dst >> 8 (dst < 50000 -> 0..195)
#define BINCAP 16384   // padded CSR slots per bin (expected ~10000)

typedef int      vint4   __attribute__((ext_vector_type(4)));
typedef float    vfloat4 __attribute__((ext_vector_type(4)));
typedef float    floatx4 __attribute__((ext_vector_type(4)));
typedef float    vfloat2 __attribute__((ext_vector_type(2)));
typedef unsigned vuint4  __attribute__((ext_vector_type(4)));
typedef _Float16 half2v  __attribute__((ext_vector_type(2)));
typedef _Float16 half8   __attribute__((ext_vector_type(8)));

__device__ __forceinline__ half8 cvt8(vfloat4 a, vfloat4 b) {
    half8 r;
    r[0] = (_Float16)a.x; r[1] = (_Float16)a.y; r[2] = (_Float16)a.z; r[3] = (_Float16)a.w;
    r[4] = (_Float16)b.x; r[5] = (_Float16)b.y; r[6] = (_Float16)b.z; r[7] = (_Float16)b.w;
    return r;
}

__device__ __forceinline__ vfloat2 dec8(unsigned v) {
    // fp8 e4m3 pair (bytes 0,1 of low word) -> 2x f32
    return __builtin_amdgcn_cvt_pk_f32_fp8((int)v, false);
}

// ---------------- fused init: W->frag cvt | zero pooled | zero sentinel row ----------
__global__ void initcvt_kernel(const float* __restrict__ W0, const float* __restrict__ W1,
                               const float* __restrict__ W2, half8* __restrict__ wf,
                               float* __restrict__ pooled, unsigned short* __restrict__ tab8) {
    int b = blockIdx.x;
    if (b < 3) {
        const float* Ws[3] = {W0, W1, W2};
        const float* W = Ws[b];
        half8* outp = wf + (size_t)b * 2048;
        for (int idx = threadIdx.x; idx < 2048; idx += 256) {
            int t = idx >> 9;
            int n = (idx >> 6) & 7;
            int ln = idx & 63;
            int q = ln >> 4, c = ln & 15;
            const float* wp = W + (t * 32 + q * 8) * DIM + n * 16 + c;
            half8 f;
#pragma unroll
            for (int j = 0; j < 8; ++j) f[j] = (_Float16)wp[j * DIM];
            outp[idx] = f;
        }
    } else {
        if (b == 3 && threadIdx.x < 64)      // zero sentinel row NN of fp8 table
            tab8[(size_t)NN * 64 + threadIdx.x] = 0;
        int k = (b - 3) * 256 + threadIdx.x;
        if (k < NG * DIM) pooled[k] = 0.f;
    }
}

// ---------------- pass1: LDS counting-sort each 4096-edge tile by bin ----------------
__launch_bounds__(256, 2)
__global__ void pass1_kernel(const int* __restrict__ src, const int* __restrict__ dst,
                             unsigned* __restrict__ chunks, int* __restrict__ lexg) {
    __shared__ unsigned sorted[CHSZ];
    __shared__ int h[256], lex[257], c2[256];
    int t = threadIdx.x;
    int c = blockIdx.x;
    int e0 = c * CHSZ;
    int nrec = NE - e0; if (nrec > CHSZ) nrec = CHSZ;
    h[t] = 0;
    __syncthreads();
    unsigned myrec[16];
#pragma unroll
    for (int j = 0; j < 16; ++j) {
        int i = t + j * 256;
        if (i < nrec) {
            int e = e0 + i;
            int d = __builtin_nontemporal_load(dst + e);
            int s = __builtin_nontemporal_load(src + e);
            myrec[j] = (unsigned)s | ((unsigned)(d & 255) << 16) | ((unsigned)(d >> 8) << 24);
            atomicAdd(&h[d >> 8], 1);
        } else myrec[j] = 0xFFFFFFFFu;
    }
    __syncthreads();
    if (t < 64) {               // wave-0 exclusive scan of h[0..255]
        int base = t * 4;
        int v0 = h[base], v1 = h[base + 1], v2 = h[base + 2], v3 = h[base + 3];
        int s = v0 + v1 + v2 + v3;
        int inc = s;
#pragma unroll
        for (int o = 1; o < 64; o <<= 1) {
            int u = __shfl_up(inc, o);
            if (t >= o) inc += u;
        }
        int pre = inc - s;
        lex[base] = pre;
        lex[base + 1] = pre + v0;
        lex[base + 2] = pre + v0 + v1;
        lex[base + 3] = pre + v0 + v1 + v2;
        if (t == 63) lex[256] = inc;
    }
    c2[t] = 0;
    __syncthreads();
#pragma unroll
    for (int j = 0; j < 16; ++j) {
        unsigned rec = myrec[j];
        if (rec != 0xFFFFFFFFu) {
            int bb = rec >> 24;
            int pos = lex[bb] + atomicAdd(&c2[bb], 1);
            sorted[pos] = rec;
        }
    }
    __syncthreads();
    for (int j = t; j < nrec; j += 256)
        __builtin_nontemporal_store(sorted[j], chunks + (size_t)c * CHSZ + j);
    if (t < 197) lexg[c * 197 + t] = lex[t];
}

// ---------------- pass2: per-bin 2-pass histogram+scatter; padded aligned CSR --------
// recs[] staging removed: chunk segments are read twice from L2/L3 (12.8 MB total).
// 8 lanes cooperate per chunk (8x record-loop parallelism). LDS 38 KB -> 4 blocks/CU.
__launch_bounds__(256, 4)
__global__ void pass2_kernel(const unsigned* __restrict__ chunks, const int* __restrict__ lexg,
                             unsigned short* __restrict__ edges, int* __restrict__ rowbeg,
                             int* __restrict__ cntn, float* __restrict__ dq) {
    __shared__ unsigned short outb[BINCAP];   // 32 KB
    __shared__ int sbeg[NCH], slen[NCH];      // 3.1 KB
    __shared__ int h[256], off[257], c2[256];
    int t = threadIdx.x;
    int b = blockIdx.x;   // 0..195
    unsigned sent = (unsigned)NN | ((unsigned)NN << 16);
    for (int i = t; i < BINCAP / 2; i += 256) ((unsigned*)outb)[i] = sent;  // sentinel pad
    for (int c = t; c < NCH; c += 256) {
        int s0 = lexg[c * 197 + b];
        sbeg[c] = s0;
        slen[c] = lexg[c * 197 + b + 1] - s0;
    }
    h[t] = 0;
    __syncthreads();
    int g  = t >> 3;       // chunk group 0..31
    int lj = t & 7;        // lane within group
    // pass A: histogram node-low-bytes
    for (int c = g; c < NCH; c += 32) {
        const unsigned* cp = chunks + (size_t)c * CHSZ + sbeg[c];
        int len = slen[c];
        for (int j = lj; j < len; j += 8)
            atomicAdd(&h[(cp[j] >> 16) & 255], 1);
    }
    __syncthreads();
    if (t < 64) {               // wave-0 exclusive scan of ceil8(h)
        int base = t * 4;
        int v0 = (h[base] + 7) & ~7,     v1 = (h[base + 1] + 7) & ~7;
        int v2 = (h[base + 2] + 7) & ~7, v3 = (h[base + 3] + 7) & ~7;
        int s = v0 + v1 + v2 + v3;
        int inc = s;
#pragma unroll
        for (int o = 1; o < 64; o <<= 1) {
            int u = __shfl_up(inc, o);
            if (t >= o) inc += u;
        }
        int pre = inc - s;
        off[base] = pre;
        off[base + 1] = pre + v0;
        off[base + 2] = pre + v0 + v1;
        off[base + 3] = pre + v0 + v1 + v2;
        if (t == 63) off[256] = inc;
    }
    c2[t] = 0;
    __syncthreads();
    // pass B: scatter src indices into padded per-node slots
    for (int c = g; c < NCH; c += 32) {
        const unsigned* cp = chunks + (size_t)c * CHSZ + sbeg[c];
        int len = slen[c];
        for (int j = lj; j < len; j += 8) {
            unsigned rec = cp[j];
            int dl = (rec >> 16) & 255;
            int r = atomicAdd(&c2[dl], 1);
            outb[off[dl] + r] = (unsigned short)(rec & 0xFFFFu);
        }
    }
    __syncthreads();
    int ptot = off[256];
    int B = b * BINCAP;
    for (int i = t; i < ptot; i += 256)
        edges[B + i] = outb[i];
    int node = b * 256 + t;
    if (node < NN) {
        rowbeg[node] = B + off[t];
        int d = h[t];
        cntn[node] = d;
        dq[node] = 1.0f / sqrtf((float)(d + 1));
    }
}

// ---------------- layer-0 GEMM: fp32 x in, fp8 table out ----------------
// Table row = 64 byte-pairs; pair p holds features (p, p+64), value = 64*dq*(x@W).
__launch_bounds__(256, 4)
__global__ void gemm0_mfma(const float* __restrict__ x, const half8* __restrict__ wfl,
                           const float* __restrict__ dq, unsigned short* __restrict__ t8) {
    __shared__ half8 Wf[2048];   // 32 KB
    int tid = threadIdx.x;
    for (int idx = tid; idx < 2048; idx += 256) Wf[idx] = wfl[idx];
    __syncthreads();
    int wid = tid >> 6, lane = tid & 63;
    int q = lane >> 4, m = lane & 15;
    int r0 = blockIdx.x * 64 + wid * 16;
    int arow = r0 + m;
    if (arow > NN - 1) arow = NN - 1;
    const vfloat4* ap = (const vfloat4*)(x + (size_t)arow * DIM + q * 8);
    half8 a0 = cvt8(ap[0],  ap[1]);
    half8 a1 = cvt8(ap[8],  ap[9]);
    half8 a2 = cvt8(ap[16], ap[17]);
    half8 a3 = cvt8(ap[24], ap[25]);
    floatx4 acc[8];
#pragma unroll
    for (int n = 0; n < 8; ++n) acc[n] = (floatx4){0.f, 0.f, 0.f, 0.f};
#pragma unroll
    for (int n = 0; n < 8; ++n)
        acc[n] = __builtin_amdgcn_mfma_f32_16x16x32_f16(a0, Wf[(0 * 8 + n) * 64 + lane], acc[n], 0, 0, 0);
#pragma unroll
    for (int n = 0; n < 8; ++n)
        acc[n] = __builtin_amdgcn_mfma_f32_16x16x32_f16(a1, Wf[(1 * 8 + n) * 64 + lane], acc[n], 0, 0, 0);
#pragma unroll
    for (int n = 0; n < 8; ++n)
        acc[n] = __builtin_amdgcn_mfma_f32_16x16x32_f16(a2, Wf[(2 * 8 + n) * 64 + lane], acc[n], 0, 0, 0);
#pragma unroll
    for (int n = 0; n < 8; ++n)
        acc[n] = __builtin_amdgcn_mfma_f32_16x16x32_f16(a3, Wf[(3 * 8 + n) * 64 + lane], acc[n], 0, 0, 0);
    float dqr[4];
#pragma unroll
    for (int r = 0; r < 4; ++r) {
        int row = r0 + q * 4 + r;
        dqr[r] = (row < NN) ? dq[row] * 64.f : 0.f;
    }
#pragma unroll
    for (int n = 0; n < 4; ++n) {
#pragma unroll
        for (int r = 0; r < 4; ++r) {
            int row = r0 + q * 4 + r;
            if (row < NN) {
                unsigned p = __builtin_amdgcn_cvt_pk_fp8_f32(
                    acc[n][r] * dqr[r], acc[n + 4][r] * dqr[r], 0, false);
                t8[(size_t)row * 64 + n * 16 + m] = (unsigned short)p;
            }
        }
    }
}

// ---------------- GEMM via MFMA: fp16 activations in, fp8 table out -----------------
__launch_bounds__(256, 4)
__global__ void gemm_mfma(const _Float16* __restrict__ yin, const half8* __restrict__ wfl,
                          const float* __restrict__ dq, unsigned short* __restrict__ t8) {
    __shared__ half8 Wf[2048];   // 32 KB
    int tid = threadIdx.x;
    for (int idx = tid; idx < 2048; idx += 256) Wf[idx] = wfl[idx];
    __syncthreads();
    int wid = tid >> 6, lane = tid & 63;
    int q = lane >> 4, m = lane & 15;
    int r0 = blockIdx.x * 64 + wid * 16;
    int arow = r0 + m;
    if (arow > NN - 1) arow = NN - 1;
    const half8* ap = (const half8*)(yin + (size_t)arow * DIM + q * 8);
    half8 a0 = ap[0], a1 = ap[4], a2 = ap[8], a3 = ap[12];
    floatx4 acc[8];
#pragma unroll
    for (int n = 0; n < 8; ++n) acc[n] = (floatx4){0.f, 0.f, 0.f, 0.f};
#pragma unroll
    for (int n = 0; n < 8; ++n)
        acc[n] = __builtin_amdgcn_mfma_f32_16x16x32_f16(a0, Wf[(0 * 8 + n) * 64 + lane], acc[n], 0, 0, 0);
#pragma unroll
    for (int n = 0; n < 8; ++n)
        acc[n] = __builtin_amdgcn_mfma_f32_16x16x32_f16(a1, Wf[(1 * 8 + n) * 64 + lane], acc[n], 0, 0, 0);
#pragma unroll
    for (int n = 0; n < 8; ++n)
        acc[n] = __builtin_amdgcn_mfma_f32_16x16x32_f16(a2, Wf[(2 * 8 + n) * 64 + lane], acc[n], 0, 0, 0);
#pragma unroll
    for (int n = 0; n < 8; ++n)
        acc[n] = __builtin_amdgcn_mfma_f32_16x16x32_f16(a3, Wf[(3 * 8 + n) * 64 + lane], acc[n], 0, 0, 0);
    float dqr[4];
#pragma unroll
    for (int r = 0; r < 4; ++r) {
        int row = r0 + q * 4 + r;
        dqr[r] = (row < NN) ? dq[row] * 64.f : 0.f;
    }
#pragma unroll
    for (int n = 0; n < 4; ++n) {
#pragma unroll
        for (int r = 0; r < 4; ++r) {
            int row = r0 + q * 4 + r;
            if (row < NN) {
                unsigned p = __builtin_amdgcn_cvt_pk_fp8_f32(
                    acc[n][r] * dqr[r], acc[n + 4][r] * dqr[r], 0, false);
                t8[(size_t)row * 64 + n * 16 + m] = (unsigned short)p;
            }
        }
    }
}

// ---------------- fused conv: fp8 gather (2B/lane), 16 wave-uniform rows in flight ----
// t[i] = 64*dq[i]*(h@W)[i] in fp8; lane l holds features (l, l+64).
// out_prenorm = (sum_src t + t_self) * (dq_dst/64) + b.  Pad slots -> sentinel row NN.
__launch_bounds__(256, 8)
__global__ void conv_kernel(const unsigned short* __restrict__ t8, const float* __restrict__ bias,
                            const int* __restrict__ rowbeg, const int* __restrict__ cntn,
                            const unsigned short* __restrict__ edges, const float* __restrict__ dq,
                            _Float16* __restrict__ out, const int* __restrict__ batch,
                            float* __restrict__ pooled, int do_pool) {
    int wid = threadIdx.x >> 6;
    int lane = threadIdx.x & 63;
    int node = blockIdx.x * 4 + wid;
    if (node >= NN) return;
    int deg = cntn[node];
    int degP = (deg + 7) & ~7;                         // padded with sentinel slots
    const unsigned short* ep = edges + rowbeg[node];   // 16B-aligned (8-slot padding)
    // epilogue loads issued early: latency hides under the gather loop
    float dqd = dq[node];
    unsigned short sv = t8[(size_t)node * 64 + lane];  // self row
    float b_lo = bias[lane], b_hi = bias[lane + 64];
    vfloat2 c0 = {0.f, 0.f}, c1 = c0, c2 = c0, c3 = c0;
    int e = 0;
    for (; e + 16 <= degP; e += 16) {
        vuint4 pk0 = __builtin_nontemporal_load((const vuint4*)(ep + e));
        vuint4 pk1 = __builtin_nontemporal_load((const vuint4*)(ep + e + 8));
        unsigned short w0 = t8[(size_t)(pk0.x & 0xFFFFu) * 64 + lane];
        unsigned short w1 = t8[(size_t)(pk0.x >> 16)     * 64 + lane];
        unsigned short w2 = t8[(size_t)(pk0.y & 0xFFFFu) * 64 + lane];
        unsigned short w3 = t8[(size_t)(pk0.y >> 16)     * 64 + lane];
        unsigned short w4 = t8[(size_t)(pk0.z & 0xFFFFu) * 64 + lane];
        unsigned short w5 = t8[(size_t)(pk0.z >> 16)     * 64 + lane];
        unsigned short w6 = t8[(size_t)(pk0.w & 0xFFFFu) * 64 + lane];
        unsigned short w7 = t8[(size_t)(pk0.w >> 16)     * 64 + lane];
        unsigned short w8 = t8[(size_t)(pk1.x & 0xFFFFu) * 64 + lane];
        unsigned short w9 = t8[(size_t)(pk1.x >> 16)     * 64 + lane];
        unsigned short wa = t8[(size_t)(pk1.y & 0xFFFFu) * 64 + lane];
        unsigned short wb = t8[(size_t)(pk1.y >> 16)     * 64 + lane];
        unsigned short wc = t8[(size_t)(pk1.z & 0xFFFFu) * 64 + lane];
        unsigned short wd = t8[(size_t)(pk1.z >> 16)     * 64 + lane];
        unsigned short we = t8[(size_t)(pk1.w & 0xFFFFu) * 64 + lane];
        unsigned short wf = t8[(size_t)(pk1.w >> 16)     * 64 + lane];
        c0 += dec8(w0); c1 += dec8(w1); c2 += dec8(w2); c3 += dec8(w3);
        c0 += dec8(w4); c1 += dec8(w5); c2 += dec8(w6); c3 += dec8(w7);
        c0 += dec8(w8); c1 += dec8(w9); c2 += dec8(wa); c3 += dec8(wb);
        c0 += dec8(wc); c1 += dec8(wd); c2 += dec8(we); c3 += dec8(wf);
    }
    if (e < degP) {   // one padded 8-block
        vuint4 pk = __builtin_nontemporal_load((const vuint4*)(ep + e));
        unsigned short w0 = t8[(size_t)(pk.x & 0xFFFFu) * 64 + lane];
        unsigned short w1 = t8[(size_t)(pk.x >> 16)     * 64 + lane];
        unsigned short w2 = t8[(size_t)(pk.y & 0xFFFFu) * 64 + lane];
        unsigned short w3 = t8[(size_t)(pk.y >> 16)     * 64 + lane];
        unsigned short w4 = t8[(size_t)(pk.z & 0xFFFFu) * 64 + lane];
        unsigned short w5 = t8[(size_t)(pk.z >> 16)     * 64 + lane];
        unsigned short w6 = t8[(size_t)(pk.w & 0xFFFFu) * 64 + lane];
        unsigned short w7 = t8[(size_t)(pk.w >> 16)     * 64 + lane];
        c0 += dec8(w0); c1 += dec8(w1); c2 += dec8(w2); c3 += dec8(w3);
        c0 += dec8(w4); c1 += dec8(w5); c2 += dec8(w6); c3 += dec8(w7);
    }
    float sx = c0.x + c1.x + c2.x + c3.x;
    float sy = c0.y + c1.y + c2.y + c3.y;
    vfloat2 sf = dec8(sv);
    float sc = dqd * 0.015625f;   // fold the 1/64 table scale into dq_dst
    float ax = (sx + sf.x) * sc + b_lo;
    float ay = (sy + sf.y) * sc + b_hi;
    float ss = ax * ax + ay * ay;
#pragma unroll
    for (int off = 32; off; off >>= 1) ss += __shfl_xor(ss, off);
    float inv = 1.0f / fmaxf(sqrtf(ss), 1e-12f);
    float ox = fmaxf(ax * inv, 0.f);
    float oy = fmaxf(ay * inv, 0.f);
    if (!do_pool) {
        out[(size_t)node * DIM + lane]      = (_Float16)ox;   // feature l
        out[(size_t)node * DIM + 64 + lane] = (_Float16)oy;   // feature l+64
    } else {
        int g = batch[node];
        atomicAdd(&pooled[g * DIM + lane], ox);
        atomicAdd(&pooled[g * DIM + 64 + lane], oy);
    }
}

// ---------------- head: z = relu(pooled@W1+b1); logits = z@W2+b2 ----------------
__launch_bounds__(128)
__global__ void head_kernel(const float* __restrict__ pooled, const float* __restrict__ w1,
                            const float* __restrict__ b1, const float* __restrict__ w2,
                            const float* __restrict__ b2, float* __restrict__ out) {
    __shared__ float sp[DIM];
    __shared__ float red[4];
    int g = blockIdx.x;
    int k = threadIdx.x;
    sp[k] = pooled[g * DIM + k];
    __syncthreads();
    float acc = b1[k];
#pragma unroll 8
    for (int j = 0; j < DIM; ++j) acc += sp[j] * w1[j * DIM + k];
    float z = fmaxf(acc, 0.f);
    float p0 = z * w2[k * 2 + 0];
    float p1 = z * w2[k * 2 + 1];
#pragma unroll
    for (int off = 32; off; off >>= 1) {
        p0 += __shfl_xor(p0, off);
        p1 += __shfl_xor(p1, off);
    }
    if ((k & 63) == 0) {
        red[(k >> 6) * 2 + 0] = p0;
        red[(k >> 6) * 2 + 1] = p1;
    }
    __syncthreads();
    if (k == 0) {
        out[g * 2 + 0] = red[0] + red[2] + b2[0];
        out[g * 2 + 1] = red[1] + red[3] + b2[1];
    }
}

extern "C" void kernel_launch(void* const* d_in, const int* in_sizes, int n_in,
                              void* d_out, int out_size, void* d_ws, size_t ws_size,
                              hipStream_t stream) {
    const float* x    = (const float*)d_in[0];
    const int* eidx   = (const int*)d_in[1];
    const int* batch  = (const int*)d_in[2];
    const float* W0   = (const float*)d_in[3];
    const float* b0   = (const float*)d_in[4];
    const float* W1   = (const float*)d_in[5];
    const float* b1   = (const float*)d_in[6];
    const float* W2   = (const float*)d_in[7];
    const float* b2   = (const float*)d_in[8];
    const float* l1w  = (const float*)d_in[9];
    const float* l1b  = (const float*)d_in[10];
    const float* l2w  = (const float*)d_in[11];
    const float* l2b  = (const float*)d_in[12];
    float* out = (float*)d_out;

    #define ALIGN256(v) (((size_t)(v) + 255) & ~(size_t)255)
    char* w = (char*)d_ws;
    float* dq     = (float*)w; w += ALIGN256((size_t)NN * 4);
    int*   rowbeg = (int*)w;   w += ALIGN256((size_t)NN * 4);
    int*   cntn   = (int*)w;   w += ALIGN256((size_t)NN * 4);
    int*   lexg   = (int*)w;   w += ALIGN256((size_t)NCH * 197 * 4);
    unsigned* chunks = (unsigned*)w; w += ALIGN256((size_t)NCH * CHSZ * 4);
    unsigned short* edges = (unsigned short*)w; w += ALIGN256((size_t)NBINS * BINCAP * 2);
    half8* wf     = (half8*)w; w += ALIGN256((size_t)3 * 2048 * 16);
    unsigned short* tab8 = (unsigned short*)w; w += ALIGN256((size_t)(NN + 1) * 64 * 2);
    _Float16* bufy = (_Float16*)w; w += ALIGN256((size_t)NN * DIM * 2);
    float* pooled = (float*)w; w += ALIGN256((size_t)NG * DIM * 4);

    const int* src = eidx;
    const int* dst = eidx + NE;

    initcvt_kernel<<<3 + (NG * DIM + 255) / 256, 256, 0, stream>>>(W0, W1, W2, wf, pooled, tab8);
    pass1_kernel<<<NCH, 256, 0, stream>>>(src, dst, chunks, lexg);
    pass2_kernel<<<NBINS, 256, 0, stream>>>(chunks, lexg, edges, rowbeg, cntn, dq);

    const int CG = (NN + 3) / 4;        // 12500 blocks, one wave per node
    const int GG = (NN + 63) / 64;      // 782 blocks, one 64-row group per block

    gemm0_mfma<<<GG, 256, 0, stream>>>(x, wf, dq, tab8);
    conv_kernel<<<CG, 256, 0, stream>>>(tab8, b0, rowbeg, cntn, edges, dq,
                                        bufy, batch, pooled, 0);
    gemm_mfma<<<GG, 256, 0, stream>>>(bufy, wf + 2048, dq, tab8);
    conv_kernel<<<CG, 256, 0, stream>>>(tab8, b1, rowbeg, cntn, edges, dq,
                                        bufy, batch, pooled, 0);
    gemm_mfma<<<GG, 256, 0, stream>>>(bufy, wf + 4096, dq, tab8);
    conv_kernel<<<CG, 256, 0, stream>>>(tab8, b2, rowbeg, cntn, edges, dq,
                                        bufy, batch, pooled, 1);
    head_kernel<<<NG, 128, 0, stream>>>(pooled, l1w, l1b, l2w, l2b, out);
}

// Round 9
// 267.994 us; speedup vs baseline: 1.0709x; 1.0709x over previous
//
#include <hip/hip_runtime.h>

#define NN 50000
#define NE 1600000
#define DIM 128
#define NG  512
#define NCH 391        // ceil(NE/4096) edge chunks
#define CHSZ 4096
#define NBINS 196      // bin = dst >> 8 (dst < 50000 -> 0..195)
#define BINCAP 16384   // padded CSR slots per bin (expected ~10000)

typedef int      vint4   __attribute__((ext_vector_type(4)));
typedef float    vfloat4 __attribute__((ext_vector_type(4)));
typedef float    floatx4 __attribute__((ext_vector_type(4)));
typedef float    vfloat2 __attribute__((ext_vector_type(2)));
typedef unsigned vuint4  __attribute__((ext_vector_type(4)));
typedef _Float16 half2v  __attribute__((ext_vector_type(2)));
typedef _Float16 half8   __attribute__((ext_vector_type(8)));

__device__ __forceinline__ half8 cvt8(vfloat4 a, vfloat4 b) {
    half8 r;
    r[0] = (_Float16)a.x; r[1] = (_Float16)a.y; r[2] = (_Float16)a.z; r[3] = (_Float16)a.w;
    r[4] = (_Float16)b.x; r[5] = (_Float16)b.y; r[6] = (_Float16)b.z; r[7] = (_Float16)b.w;
    return r;
}

__device__ __forceinline__ vfloat2 dec8(unsigned v) {
    // fp8 e4m3 pair (bytes 0,1 of low word) -> 2x f32
    return __builtin_amdgcn_cvt_pk_f32_fp8((int)v, false);
}

// ---------------- fused init: W->frag cvt | zero pooled | zero sentinel row ----------
__global__ void initcvt_kernel(const float* __restrict__ W0, const float* __restrict__ W1,
                               const float* __restrict__ W2, half8* __restrict__ wf,
                               float* __restrict__ pooled, unsigned short* __restrict__ tab8) {
    int b = blockIdx.x;
    if (b < 3) {
        const float* Ws[3] = {W0, W1, W2};
        const float* W = Ws[b];
        half8* outp = wf + (size_t)b * 2048;
        for (int idx = threadIdx.x; idx < 2048; idx += 256) {
            int t = idx >> 9;
            int n = (idx >> 6) & 7;
            int ln = idx & 63;
            int q = ln >> 4, c = ln & 15;
            const float* wp = W + (t * 32 + q * 8) * DIM + n * 16 + c;
            half8 f;
#pragma unroll
            for (int j = 0; j < 8; ++j) f[j] = (_Float16)wp[j * DIM];
            outp[idx] = f;
        }
    } else {
        if (b == 3 && threadIdx.x < 64)      // zero sentinel row NN of fp8 table
            tab8[(size_t)NN * 64 + threadIdx.x] = 0;
        int k = (b - 3) * 256 + threadIdx.x;
        if (k < NG * DIM) pooled[k] = 0.f;
    }
}

// ---------------- pass1: LDS counting-sort each 4096-edge tile by bin ----------------
__launch_bounds__(256, 2)
__global__ void pass1_kernel(const int* __restrict__ src, const int* __restrict__ dst,
                             unsigned* __restrict__ chunks, int* __restrict__ lexg) {
    __shared__ unsigned sorted[CHSZ];
    __shared__ int h[256], lex[257], c2[256];
    int t = threadIdx.x;
    int c = blockIdx.x;
    int e0 = c * CHSZ;
    int nrec = NE - e0; if (nrec > CHSZ) nrec = CHSZ;
    h[t] = 0;
    __syncthreads();
    unsigned myrec[16];
#pragma unroll
    for (int j = 0; j < 16; ++j) {
        int i = t + j * 256;
        if (i < nrec) {
            int e = e0 + i;
            int d = __builtin_nontemporal_load(dst + e);
            int s = __builtin_nontemporal_load(src + e);
            myrec[j] = (unsigned)s | ((unsigned)(d & 255) << 16) | ((unsigned)(d >> 8) << 24);
            atomicAdd(&h[d >> 8], 1);
        } else myrec[j] = 0xFFFFFFFFu;
    }
    __syncthreads();
    if (t < 64) {               // wave-0 exclusive scan of h[0..255]
        int base = t * 4;
        int v0 = h[base], v1 = h[base + 1], v2 = h[base + 2], v3 = h[base + 3];
        int s = v0 + v1 + v2 + v3;
        int inc = s;
#pragma unroll
        for (int o = 1; o < 64; o <<= 1) {
            int u = __shfl_up(inc, o);
            if (t >= o) inc += u;
        }
        int pre = inc - s;
        lex[base] = pre;
        lex[base + 1] = pre + v0;
        lex[base + 2] = pre + v0 + v1;
        lex[base + 3] = pre + v0 + v1 + v2;
        if (t == 63) lex[256] = inc;
    }
    c2[t] = 0;
    __syncthreads();
#pragma unroll
    for (int j = 0; j < 16; ++j) {
        unsigned rec = myrec[j];
        if (rec != 0xFFFFFFFFu) {
            int bb = rec >> 24;
            int pos = lex[bb] + atomicAdd(&c2[bb], 1);
            sorted[pos] = rec;
        }
    }
    __syncthreads();
    for (int j = t; j < nrec; j += 256)
        __builtin_nontemporal_store(sorted[j], chunks + (size_t)c * CHSZ + j);
    if (t < 197) lexg[c * 197 + t] = lex[t];
}

// ---------------- pass2: per-bin 2-pass histogram+scatter; padded aligned CSR --------
__launch_bounds__(256, 4)
__global__ void pass2_kernel(const unsigned* __restrict__ chunks, const int* __restrict__ lexg,
                             unsigned short* __restrict__ edges, int* __restrict__ rowbeg,
                             int* __restrict__ cntn, float* __restrict__ dq) {
    __shared__ unsigned short outb[BINCAP];   // 32 KB
    __shared__ int sbeg[NCH], slen[NCH];      // 3.1 KB
    __shared__ int h[256], off[257], c2[256];
    int t = threadIdx.x;
    int b = blockIdx.x;   // 0..195
    unsigned sent = (unsigned)NN | ((unsigned)NN << 16);
    for (int i = t; i < BINCAP / 2; i += 256) ((unsigned*)outb)[i] = sent;  // sentinel pad
    for (int c = t; c < NCH; c += 256) {
        int s0 = lexg[c * 197 + b];
        sbeg[c] = s0;
        slen[c] = lexg[c * 197 + b + 1] - s0;
    }
    h[t] = 0;
    __syncthreads();
    int g  = t >> 3;       // chunk group 0..31
    int lj = t & 7;        // lane within group
    // pass A: histogram node-low-bytes
    for (int c = g; c < NCH; c += 32) {
        const unsigned* cp = chunks + (size_t)c * CHSZ + sbeg[c];
        int len = slen[c];
        for (int j = lj; j < len; j += 8)
            atomicAdd(&h[(cp[j] >> 16) & 255], 1);
    }
    __syncthreads();
    if (t < 64) {               // wave-0 exclusive scan of ceil8(h)
        int base = t * 4;
        int v0 = (h[base] + 7) & ~7,     v1 = (h[base + 1] + 7) & ~7;
        int v2 = (h[base + 2] + 7) & ~7, v3 = (h[base + 3] + 7) & ~7;
        int s = v0 + v1 + v2 + v3;
        int inc = s;
#pragma unroll
        for (int o = 1; o < 64; o <<= 1) {
            int u = __shfl_up(inc, o);
            if (t >= o) inc += u;
        }
        int pre = inc - s;
        off[base] = pre;
        off[base + 1] = pre + v0;
        off[base + 2] = pre + v0 + v1;
        off[base + 3] = pre + v0 + v1 + v2;
        if (t == 63) off[256] = inc;
    }
    c2[t] = 0;
    __syncthreads();
    // pass B: scatter src indices into padded per-node slots
    for (int c = g; c < NCH; c += 32) {
        const unsigned* cp = chunks + (size_t)c * CHSZ + sbeg[c];
        int len = slen[c];
        for (int j = lj; j < len; j += 8) {
            unsigned rec = cp[j];
            int dl = (rec >> 16) & 255;
            int r = atomicAdd(&c2[dl], 1);
            outb[off[dl] + r] = (unsigned short)(rec & 0xFFFFu);
        }
    }
    __syncthreads();
    int ptot = off[256];
    int B = b * BINCAP;
    for (int i = t; i < ptot; i += 256)
        edges[B + i] = outb[i];
    int node = b * 256 + t;
    if (node < NN) {
        rowbeg[node] = B + off[t];
        int d = h[t];
        cntn[node] = d;
        dq[node] = 1.0f / sqrtf((float)(d + 1));
    }
}

// ---------------- layer-0 GEMM: fp32 x in, fp8 table out ----------------
// Table row = 64 byte-pairs; pair p holds features (p, p+64), value = 64*dq*(x@W).
__launch_bounds__(256, 4)
__global__ void gemm0_mfma(const float* __restrict__ x, const half8* __restrict__ wfl,
                           const float* __restrict__ dq, unsigned short* __restrict__ t8) {
    __shared__ half8 Wf[2048];   // 32 KB
    int tid = threadIdx.x;
    for (int idx = tid; idx < 2048; idx += 256) Wf[idx] = wfl[idx];
    __syncthreads();
    int wid = tid >> 6, lane = tid & 63;
    int q = lane >> 4, m = lane & 15;
    int r0 = blockIdx.x * 64 + wid * 16;
    int arow = r0 + m;
    if (arow > NN - 1) arow = NN - 1;
    const vfloat4* ap = (const vfloat4*)(x + (size_t)arow * DIM + q * 8);
    half8 a0 = cvt8(ap[0],  ap[1]);
    half8 a1 = cvt8(ap[8],  ap[9]);
    half8 a2 = cvt8(ap[16], ap[17]);
    half8 a3 = cvt8(ap[24], ap[25]);
    floatx4 acc[8];
#pragma unroll
    for (int n = 0; n < 8; ++n) acc[n] = (floatx4){0.f, 0.f, 0.f, 0.f};
#pragma unroll
    for (int n = 0; n < 8; ++n)
        acc[n] = __builtin_amdgcn_mfma_f32_16x16x32_f16(a0, Wf[(0 * 8 + n) * 64 + lane], acc[n], 0, 0, 0);
#pragma unroll
    for (int n = 0; n < 8; ++n)
        acc[n] = __builtin_amdgcn_mfma_f32_16x16x32_f16(a1, Wf[(1 * 8 + n) * 64 + lane], acc[n], 0, 0, 0);
#pragma unroll
    for (int n = 0; n < 8; ++n)
        acc[n] = __builtin_amdgcn_mfma_f32_16x16x32_f16(a2, Wf[(2 * 8 + n) * 64 + lane], acc[n], 0, 0, 0);
#pragma unroll
    for (int n = 0; n < 8; ++n)
        acc[n] = __builtin_amdgcn_mfma_f32_16x16x32_f16(a3, Wf[(3 * 8 + n) * 64 + lane], acc[n], 0, 0, 0);
    float dqr[4];
#pragma unroll
    for (int r = 0; r < 4; ++r) {
        int row = r0 + q * 4 + r;
        dqr[r] = (row < NN) ? dq[row] * 64.f : 0.f;
    }
#pragma unroll
    for (int n = 0; n < 4; ++n) {
#pragma unroll
        for (int r = 0; r < 4; ++r) {
            int row = r0 + q * 4 + r;
            if (row < NN) {
                unsigned p = __builtin_amdgcn_cvt_pk_fp8_f32(
                    acc[n][r] * dqr[r], acc[n + 4][r] * dqr[r], 0, false);
                t8[(size_t)row * 64 + n * 16 + m] = (unsigned short)p;
            }
        }
    }
}

// ---------------- GEMM via MFMA: fp16 activations in, fp8 table out -----------------
__launch_bounds__(256, 4)
__global__ void gemm_mfma(const _Float16* __restrict__ yin, const half8* __restrict__ wfl,
                          const float* __restrict__ dq, unsigned short* __restrict__ t8) {
    __shared__ half8 Wf[2048];   // 32 KB
    int tid = threadIdx.x;
    for (int idx = tid; idx < 2048; idx += 256) Wf[idx] = wfl[idx];
    __syncthreads();
    int wid = tid >> 6, lane = tid & 63;
    int q = lane >> 4, m = lane & 15;
    int r0 = blockIdx.x * 64 + wid * 16;
    int arow = r0 + m;
    if (arow > NN - 1) arow = NN - 1;
    const half8* ap = (const half8*)(yin + (size_t)arow * DIM + q * 8);
    half8 a0 = ap[0], a1 = ap[4], a2 = ap[8], a3 = ap[12];
    floatx4 acc[8];
#pragma unroll
    for (int n = 0; n < 8; ++n) acc[n] = (floatx4){0.f, 0.f, 0.f, 0.f};
#pragma unroll
    for (int n = 0; n < 8; ++n)
        acc[n] = __builtin_amdgcn_mfma_f32_16x16x32_f16(a0, Wf[(0 * 8 + n) * 64 + lane], acc[n], 0, 0, 0);
#pragma unroll
    for (int n = 0; n < 8; ++n)
        acc[n] = __builtin_amdgcn_mfma_f32_16x16x32_f16(a1, Wf[(1 * 8 + n) * 64 + lane], acc[n], 0, 0, 0);
#pragma unroll
    for (int n = 0; n < 8; ++n)
        acc[n] = __builtin_amdgcn_mfma_f32_16x16x32_f16(a2, Wf[(2 * 8 + n) * 64 + lane], acc[n], 0, 0, 0);
#pragma unroll
    for (int n = 0; n < 8; ++n)
        acc[n] = __builtin_amdgcn_mfma_f32_16x16x32_f16(a3, Wf[(3 * 8 + n) * 64 + lane], acc[n], 0, 0, 0);
    float dqr[4];
#pragma unroll
    for (int r = 0; r < 4; ++r) {
        int row = r0 + q * 4 + r;
        dqr[r] = (row < NN) ? dq[row] * 64.f : 0.f;
    }
#pragma unroll
    for (int n = 0; n < 4; ++n) {
#pragma unroll
        for (int r = 0; r < 4; ++r) {
            int row = r0 + q * 4 + r;
            if (row < NN) {
                unsigned p = __builtin_amdgcn_cvt_pk_fp8_f32(
                    acc[n][r] * dqr[r], acc[n + 4][r] * dqr[r], 0, false);
                t8[(size_t)row * 64 + n * 16 + m] = (unsigned short)p;
            }
        }
    }
}

// ---------------- fused conv: SCALARIZED control/address path ------------------------
// node forced wave-uniform via readfirstlane -> deg/rowbeg/ep/edge-packets compile to
// SGPR + s_load; index extraction is SALU; gathers use saddr form (scalar base +
// loop-invariant lane offset). Per-edge VALU: 1 cvt_pk_f32_fp8 + 1 pk_add_f32.
__launch_bounds__(256, 8)
__global__ void conv_kernel(const unsigned short* __restrict__ t8, const float* __restrict__ bias,
                            const int* __restrict__ rowbeg, const int* __restrict__ cntn,
                            const unsigned short* __restrict__ edges, const float* __restrict__ dq,
                            _Float16* __restrict__ out, const int* __restrict__ batch,
                            float* __restrict__ pooled, int do_pool) {
    int wid = threadIdx.x >> 6;
    int lane = threadIdx.x & 63;
    int node = __builtin_amdgcn_readfirstlane(blockIdx.x * 4 + wid);  // wave-uniform
    if (node >= NN) return;
    int deg = cntn[node];
    int degP = (deg + 7) & ~7;                         // padded with sentinel slots
    const unsigned short* ep = edges + rowbeg[node];   // 16B-aligned (8-slot padding)
    // epilogue loads issued early: latency hides under the gather loop
    float dqd = dq[node];
    unsigned short sv = t8[(size_t)node * 64 + lane];  // self row
    float b_lo = bias[lane], b_hi = bias[lane + 64];
    vfloat2 c0 = {0.f, 0.f}, c1 = c0, c2 = c0, c3 = c0;
    int e = 0;
    for (; e + 16 <= degP; e += 16) {
        vuint4 pk0 = *(const vuint4*)(ep + e);        // uniform addr -> s_load_dwordx4
        vuint4 pk1 = *(const vuint4*)(ep + e + 8);
        unsigned short w0 = t8[(size_t)(pk0.x & 0xFFFFu) * 64 + lane];
        unsigned short w1 = t8[(size_t)(pk0.x >> 16)     * 64 + lane];
        unsigned short w2 = t8[(size_t)(pk0.y & 0xFFFFu) * 64 + lane];
        unsigned short w3 = t8[(size_t)(pk0.y >> 16)     * 64 + lane];
        unsigned short w4 = t8[(size_t)(pk0.z & 0xFFFFu) * 64 + lane];
        unsigned short w5 = t8[(size_t)(pk0.z >> 16)     * 64 + lane];
        unsigned short w6 = t8[(size_t)(pk0.w & 0xFFFFu) * 64 + lane];
        unsigned short w7 = t8[(size_t)(pk0.w >> 16)     * 64 + lane];
        unsigned short w8 = t8[(size_t)(pk1.x & 0xFFFFu) * 64 + lane];
        unsigned short w9 = t8[(size_t)(pk1.x >> 16)     * 64 + lane];
        unsigned short wa = t8[(size_t)(pk1.y & 0xFFFFu) * 64 + lane];
        unsigned short wb = t8[(size_t)(pk1.y >> 16)     * 64 + lane];
        unsigned short wc = t8[(size_t)(pk1.z & 0xFFFFu) * 64 + lane];
        unsigned short wd = t8[(size_t)(pk1.z >> 16)     * 64 + lane];
        unsigned short we = t8[(size_t)(pk1.w & 0xFFFFu) * 64 + lane];
        unsigned short wf = t8[(size_t)(pk1.w >> 16)     * 64 + lane];
        c0 += dec8(w0); c1 += dec8(w1); c2 += dec8(w2); c3 += dec8(w3);
        c0 += dec8(w4); c1 += dec8(w5); c2 += dec8(w6); c3 += dec8(w7);
        c0 += dec8(w8); c1 += dec8(w9); c2 += dec8(wa); c3 += dec8(wb);
        c0 += dec8(wc); c1 += dec8(wd); c2 += dec8(we); c3 += dec8(wf);
    }
    if (e < degP) {   // one padded 8-block
        vuint4 pk = *(const vuint4*)(ep + e);
        unsigned short w0 = t8[(size_t)(pk.x & 0xFFFFu) * 64 + lane];
        unsigned short w1 = t8[(size_t)(pk.x >> 16)     * 64 + lane];
        unsigned short w2 = t8[(size_t)(pk.y & 0xFFFFu) * 64 + lane];
        unsigned short w3 = t8[(size_t)(pk.y >> 16)     * 64 + lane];
        unsigned short w4 = t8[(size_t)(pk.z & 0xFFFFu) * 64 + lane];
        unsigned short w5 = t8[(size_t)(pk.z >> 16)     * 64 + lane];
        unsigned short w6 = t8[(size_t)(pk.w & 0xFFFFu) * 64 + lane];
        unsigned short w7 = t8[(size_t)(pk.w >> 16)     * 64 + lane];
        c0 += dec8(w0); c1 += dec8(w1); c2 += dec8(w2); c3 += dec8(w3);
        c0 += dec8(w4); c1 += dec8(w5); c2 += dec8(w6); c3 += dec8(w7);
    }
    float sx = c0.x + c1.x + c2.x + c3.x;
    float sy = c0.y + c1.y + c2.y + c3.y;
    vfloat2 sf = dec8(sv);
    float sc = dqd * 0.015625f;   // fold the 1/64 table scale into dq_dst
    float ax = (sx + sf.x) * sc + b_lo;
    float ay = (sy + sf.y) * sc + b_hi;
    float ss = ax * ax + ay * ay;
#pragma unroll
    for (int off = 32; off; off >>= 1) ss += __shfl_xor(ss, off);
    float inv = 1.0f / fmaxf(sqrtf(ss), 1e-12f);
    float ox = fmaxf(ax * inv, 0.f);
    float oy = fmaxf(ay * inv, 0.f);
    if (!do_pool) {
        out[(size_t)node * DIM + lane]      = (_Float16)ox;   // feature l
        out[(size_t)node * DIM + 64 + lane] = (_Float16)oy;   // feature l+64
    } else {
        int g = batch[node];
        atomicAdd(&pooled[g * DIM + lane], ox);
        atomicAdd(&pooled[g * DIM + 64 + lane], oy);
    }
}

// ---------------- head: z = relu(pooled@W1+b1); logits = z@W2+b2 ----------------
__launch_bounds__(128)
__global__ void head_kernel(const float* __restrict__ pooled, const float* __restrict__ w1,
                            const float* __restrict__ b1, const float* __restrict__ w2,
                            const float* __restrict__ b2, float* __restrict__ out) {
    __shared__ float sp[DIM];
    __shared__ float red[4];
    int g = blockIdx.x;
    int k = threadIdx.x;
    sp[k] = pooled[g * DIM + k];
    __syncthreads();
    float acc = b1[k];
#pragma unroll 8
    for (int j = 0; j < DIM; ++j) acc += sp[j] * w1[j * DIM + k];
    float z = fmaxf(acc, 0.f);
    float p0 = z * w2[k * 2 + 0];
    float p1 = z * w2[k * 2 + 1];
#pragma unroll
    for (int off = 32; off; off >>= 1) {
        p0 += __shfl_xor(p0, off);
        p1 += __shfl_xor(p1, off);
    }
    if ((k & 63) == 0) {
        red[(k >> 6) * 2 + 0] = p0;
        red[(k >> 6) * 2 + 1] = p1;
    }
    __syncthreads();
    if (k == 0) {
        out[g * 2 + 0] = red[0] + red[2] + b2[0];
        out[g * 2 + 1] = red[1] + red[3] + b2[1];
    }
}

extern "C" void kernel_launch(void* const* d_in, const int* in_sizes, int n_in,
                              void* d_out, int out_size, void* d_ws, size_t ws_size,
                              hipStream_t stream) {
    const float* x    = (const float*)d_in[0];
    const int* eidx   = (const int*)d_in[1];
    const int* batch  = (const int*)d_in[2];
    const float* W0   = (const float*)d_in[3];
    const float* b0   = (const float*)d_in[4];
    const float* W1   = (const float*)d_in[5];
    const float* b1   = (const float*)d_in[6];
    const float* W2   = (const float*)d_in[7];
    const float* b2   = (const float*)d_in[8];
    const float* l1w  = (const float*)d_in[9];
    const float* l1b  = (const float*)d_in[10];
    const float* l2w  = (const float*)d_in[11];
    const float* l2b  = (const float*)d_in[12];
    float* out = (float*)d_out;

    #define ALIGN256(v) (((size_t)(v) + 255) & ~(size_t)255)
    char* w = (char*)d_ws;
    float* dq     = (float*)w; w += ALIGN256((size_t)NN * 4);
    int*   rowbeg = (int*)w;   w += ALIGN256((size_t)NN * 4);
    int*   cntn   = (int*)w;   w += ALIGN256((size_t)NN * 4);
    int*   lexg   = (int*)w;   w += ALIGN256((size_t)NCH * 197 * 4);
    unsigned* chunks = (unsigned*)w; w += ALIGN256((size_t)NCH * CHSZ * 4);
    unsigned short* edges = (unsigned short*)w; w += ALIGN256((size_t)NBINS * BINCAP * 2);
    half8* wf     = (half8*)w; w += ALIGN256((size_t)3 * 2048 * 16);
    unsigned short* tab8 = (unsigned short*)w; w += ALIGN256((size_t)(NN + 1) * 64 * 2);
    _Float16* bufy = (_Float16*)w; w += ALIGN256((size_t)NN * DIM * 2);
    float* pooled = (float*)w; w += ALIGN256((size_t)NG * DIM * 4);

    const int* src = eidx;
    const int* dst = eidx + NE;

    initcvt_kernel<<<3 + (NG * DIM + 255) / 256, 256, 0, stream>>>(W0, W1, W2, wf, pooled, tab8);
    pass1_kernel<<<NCH, 256, 0, stream>>>(src, dst, chunks, lexg);
    pass2_kernel<<<NBINS, 256, 0, stream>>>(chunks, lexg, edges, rowbeg, cntn, dq);

    const int CG = (NN + 3) / 4;        // 12500 blocks, one wave per node
    const int GG = (NN + 63) / 64;      // 782 blocks, one 64-row group per block

    gemm0_mfma<<<GG, 256, 0, stream>>>(x, wf, dq, tab8);
    conv_kernel<<<CG, 256, 0, stream>>>(tab8, b0, rowbeg, cntn, edges, dq,
                                        bufy, batch, pooled, 0);
    gemm_mfma<<<GG, 256, 0, stream>>>(bufy, wf + 2048, dq, tab8);
    conv_kernel<<<CG, 256, 0, stream>>>(tab8, b1, rowbeg, cntn, edges, dq,
                                        bufy, batch, pooled, 0);
    gemm_mfma<<<GG, 256, 0, stream>>>(bufy, wf + 4096, dq, tab8);
    conv_kernel<<<CG, 256, 0, stream>>>(tab8, b2, rowbeg, cntn, edges, dq,
                                        bufy, batch, pooled, 1);
    head_kernel<<<NG, 128, 0, stream>>>(pooled, l1w, l1b, l2w, l2b, out);
}